// Round 1
// baseline (1127.558 us; speedup 1.0000x reference)
//
#include <hip/hip_runtime.h>
#include <hip/hip_bf16.h>

// Self-cdist: out[i,j] = ||x[i,:] - x[j,:]||_2, x: [16384, 32] fp32.
// GEMM-form: d2 = sq[i] + sq[j] - 2*dot(x[i],x[j]), clamp>=0, sqrt, mask.
// 128x128 tile / block (256 thr), 8x8 microtile, k-major LDS for b128 reads.

#define NROWS 16384
#define DIM 32
#define BM 128
#define BN 128

__global__ __launch_bounds__(256, 4)
void cdist_tile_kernel(const float* __restrict__ x, float* __restrict__ out) {
    __shared__ float At[DIM * BM];   // At[k*BM + row]   (k-major)
    __shared__ float Bt[DIM * BN];
    __shared__ float sqA[BM];
    __shared__ float sqB[BN];

    const int tid = threadIdx.x;
    const long i0 = (long)blockIdx.y * BM;
    const long j0 = (long)blockIdx.x * BN;

    // ---- stage tiles (global rows are contiguous: 128 rows x 32 floats = 16KB each)
    const float4* xa = (const float4*)(x + i0 * DIM);
    const float4* xb = (const float4*)(x + j0 * DIM);
#pragma unroll
    for (int s = 0; s < 4; ++s) {
        const int f   = tid + 256 * s;    // float4 index 0..1023
        const int row = f >> 3;           // 8 float4 per row
        const int k4  = (f & 7) << 2;     // base k of this float4
        const float4 va = xa[f];
        const float4 vb = xb[f];
        At[(k4 + 0) * BM + row] = va.x;
        At[(k4 + 1) * BM + row] = va.y;
        At[(k4 + 2) * BM + row] = va.z;
        At[(k4 + 3) * BM + row] = va.w;
        Bt[(k4 + 0) * BN + row] = vb.x;
        Bt[(k4 + 1) * BN + row] = vb.y;
        Bt[(k4 + 2) * BN + row] = vb.z;
        Bt[(k4 + 3) * BN + row] = vb.w;
    }

    // ---- per-row squared norms (from global; x is L2-resident).
    // fmaf ascending-k matches the dot accumulation order -> exact 0 on diagonal.
    {
        const int r = tid & 127;
        const float* base = (tid < 128) ? (x + (i0 + r) * DIM)
                                        : (x + (j0 + r) * DIM);
        float s = 0.0f;
#pragma unroll
        for (int k = 0; k < DIM; ++k) s = fmaf(base[k], base[k], s);
        if (tid < 128) sqA[r] = s; else sqB[r] = s;
    }

    __syncthreads();

    const int tx = tid & 15;   // col group
    const int ty = tid >> 4;   // row group

    float acc[8][8];
#pragma unroll
    for (int r = 0; r < 8; ++r)
#pragma unroll
        for (int c = 0; c < 8; ++c) acc[r][c] = 0.0f;

    // rows handled: 4*ty..4*ty+3 and 64+4*ty..64+4*ty+3 ; cols analogous with tx.
#pragma unroll
    for (int k = 0; k < DIM; ++k) {
        const float4* Ak = (const float4*)(At + k * BM);
        const float4* Bk = (const float4*)(Bt + k * BN);
        float a[8], b[8];
        *(float4*)&a[0] = Ak[ty];        // rows 4ty..4ty+3 (broadcast across tx)
        *(float4*)&a[4] = Ak[16 + ty];   // rows 64+4ty..
        *(float4*)&b[0] = Bk[tx];        // cols 4tx..      (2-way bank alias: free)
        *(float4*)&b[4] = Bk[16 + tx];
#pragma unroll
        for (int r = 0; r < 8; ++r)
#pragma unroll
            for (int c = 0; c < 8; ++c)
                acc[r][c] = fmaf(a[r], b[c], acc[r][c]);
    }

    // ---- epilogue: d = sqrt(max(sqA + sqB - 2*acc, 0)), 0 where d2 <= 0
    float sa[8], sb[8];
#pragma unroll
    for (int r = 0; r < 8; ++r) {
        const int ri = (r < 4) ? (4 * ty + r) : (64 + 4 * ty + (r - 4));
        sa[r] = sqA[ri];
    }
#pragma unroll
    for (int c = 0; c < 8; ++c) {
        const int cj = (c < 4) ? (4 * tx + c) : (64 + 4 * tx + (c - 4));
        sb[c] = sqB[cj];
    }

#pragma unroll
    for (int r = 0; r < 8; ++r) {
        const int  ri = (r < 4) ? (4 * ty + r) : (64 + 4 * ty + (r - 4));
        const long gi = i0 + ri;
        float* orow = out + gi * (long)NROWS + j0;
        float4 o0, o1;
        float v[8];
#pragma unroll
        for (int c = 0; c < 8; ++c) {
            float d2 = fmaf(-2.0f, acc[r][c], sa[r] + sb[c]);
            d2 = fmaxf(d2, 0.0f);
            v[c] = (d2 > 0.0f) ? sqrtf(d2) : 0.0f;
        }
        o0.x = v[0]; o0.y = v[1]; o0.z = v[2]; o0.w = v[3];
        o1.x = v[4]; o1.y = v[5]; o1.z = v[6]; o1.w = v[7];
        *(float4*)(orow + 4 * tx)      = o0;   // 16 lanes -> contiguous 256B
        *(float4*)(orow + 64 + 4 * tx) = o1;
    }
}

extern "C" void kernel_launch(void* const* d_in, const int* in_sizes, int n_in,
                              void* d_out, int out_size, void* d_ws, size_t ws_size,
                              hipStream_t stream) {
    const float* x = (const float*)d_in[0];
    float* out = (float*)d_out;
    dim3 grid(NROWS / BN, NROWS / BM);   // 128 x 128 blocks
    dim3 block(256);
    cdist_tile_kernel<<<grid, block, 0, stream>>>(x, out);
}